// Round 11
// baseline (167.758 us; speedup 1.0000x reference)
//
#include <hip/hip_runtime.h>

// Problem constants (reference: B=8, T=2048, C=1024, H=64)
#define B_ 8
#define T_ 2048
#define C_ 1024
#define H_ 64

typedef __bf16 bf16x8 __attribute__((ext_vector_type(8)));
typedef float  f32x4  __attribute__((ext_vector_type(4)));
typedef unsigned short u16x8 __attribute__((ext_vector_type(8)));
typedef float  f32x4v __attribute__((ext_vector_type(4)));

// round-half-up f32 -> bf16 bits
__device__ __forceinline__ unsigned short f2bf(float f) {
    unsigned u = __builtin_bit_cast(unsigned, f);
    u += 0x8000u;
    return (unsigned short)(u >> 16);
}

__device__ __forceinline__ float bf2f(unsigned short v) {
    unsigned u = ((unsigned)v) << 16;
    return __builtin_bit_cast(float, u);
}

__device__ __forceinline__ unsigned pack2(float lo, float hi) {
    unsigned a = __builtin_bit_cast(unsigned, lo) + 0x8000u;
    unsigned b = __builtin_bit_cast(unsigned, hi) + 0x8000u;
    return (a >> 16) | (b & 0xffff0000u);
}

union U8 { unsigned u32[4]; u16x8 v; };

__device__ __forceinline__ u16x8 cvt8v(f32x4v f0, f32x4v f1) {
    U8 r;
    r.u32[0] = pack2(f0.x, f0.y);
    r.u32[1] = pack2(f0.z, f0.w);
    r.u32[2] = pack2(f1.x, f1.y);
    r.u32[3] = pack2(f1.z, f1.w);
    return r.v;
}

__device__ __forceinline__ bf16x8 load8_bf(const unsigned short* p) {
    return __builtin_bit_cast(bf16x8, *(const u16x8*)p);
}

// Fragment-major layouts (contiguous 1KB-per-wave loads):
//   Qf/Kf[b][t16][part][l16*32 + quad*8 + j]   (t16 = seq/16, part = h/32)
//   Vf[b][s32][ht][l16*32 + quad*8 + j]        (s32 = seq/32, ht = h/16)
//   Wtf[nt][kk][l16*32 + quad*8 + j]           (nt = ncol/16 of 192, kk = c/32)

// ---------------------------------------------------------------------------
// Kernel 0: pack Wq,Wk,Wv (fp32 [C][H]) straight into fragment-major Wtf.
// ---------------------------------------------------------------------------
__global__ void cast_weights(const float* __restrict__ Wq,
                             const float* __restrict__ Wk,
                             const float* __restrict__ Wv,
                             unsigned short* __restrict__ Wtf) {
    int idx = blockIdx.x * blockDim.x + threadIdx.x;   // 0 .. 192*1024-1
    int n   = idx % 192;        // global out col
    int c   = idx / 192;        // k index
    int w   = n >> 6;
    int h   = n & 63;
    const float* W = (w == 0) ? Wq : (w == 1) ? Wk : Wv;
    int nt = n >> 4, l16 = n & 15;
    int kk = c >> 5, quad = (c >> 3) & 3, j = c & 7;
    Wtf[(size_t)(nt * 32 + kk) * 512 + l16 * 32 + quad * 8 + j] =
        f2bf(W[(size_t)c * H_ + h]);
}

// ---------------------------------------------------------------------------
// Kernel 1: fused QKV projection, v10 — kill the Wtf re-read structurally.
// Grid = B*T/128 = 128 blocks x 512 threads.  Block = 128 m-rows x 192 n x
// full K.  Wtf traffic: 128 x 384 KB = 49 MB (was 196 MB at 32-row blocks);
// x read once; total cache traffic 276 -> 129 MB.  K-loop: 16 steps of
// BK=64, x chunk (128x64 bf16, 16 KB) double-buffered in LDS; wave
// (mp=w>>1, nh=w&1) owns m-strips {2mp,2mp+1} x n-tiles [6nh,6nh+6):
// per step 4 ds_read_b128 (A) + 12 contiguous 1KB B-loads (all 8 waves load
// the same 24 KB/step -> L1 hits) + 24 MFMA; acc = 12 f32x4.
// Epilogue: each wave assembles its own 6 complete 1KB output chunks in a
// private LDS slice, then 6 contiguous 16B/lane stores.
// ---------------------------------------------------------------------------
__global__ __launch_bounds__(512) void qkv_proj(
        const float* __restrict__ x,
        const unsigned short* __restrict__ Wtf,
        unsigned short* __restrict__ Qf,
        unsigned short* __restrict__ Kf,
        unsigned short* __restrict__ Vf) {
    // dbuf staging uses [0, 16384); epilogue uses [0, 24576) (48 KB)
    __shared__ __attribute__((aligned(16))) unsigned short As_[24576];

    const int tid  = threadIdx.x;
    const int wave = tid >> 6;
    const int lane = tid & 63;
    const int l16  = lane & 15;
    const int quad = lane >> 4;
    const int mp   = wave >> 1;          // m-pair 0..3 (strips 2mp, 2mp+1)
    const int nh   = wave & 1;           // n-half (6 n-tiles)
    const size_t r0 = (size_t)blockIdx.x * 128;
    const int bb    = (int)(r0 >> 11);
    const int tloc0 = (int)(r0 & (T_ - 1));
    const int t16_0 = tloc0 >> 4;
    const int s32_0 = tloc0 >> 5;

    f32x4 acc[2][6];
#pragma unroll
    for (int st = 0; st < 2; st++)
#pragma unroll
        for (int i = 0; i < 6; i++) acc[st][i] = (f32x4){0.f, 0.f, 0.f, 0.f};

    const int loff = l16 * 32 + quad * 8;
    const unsigned short* wb = Wtf + (size_t)(nh * 6) * 32 * 512;

    // staging role: 2 granules per thread: gi = tid, tid+512
    const int row0 = tid >> 3, g0 = tid & 7;          // granule tid
    const int row1 = (tid + 512) >> 3, g1 = tid & 7;  // granule tid+512 (same g)
    const float* src0 = x + (r0 + row0) * C_ + g0 * 8;
    const float* src1 = x + (r0 + row1) * C_ + g1 * 8;
    const int off0 = row0 * 64 + ((g0 ^ (row0 & 7)) * 8);
    const int off1 = row1 * 64 + ((g1 ^ (row1 & 7)) * 8);

    // prologue: stage k-step 0 into buf 0
    {
        f32x4v a0 = *(const f32x4v*)src0;
        f32x4v a1 = *(const f32x4v*)(src0 + 4);
        f32x4v b0 = *(const f32x4v*)src1;
        f32x4v b1 = *(const f32x4v*)(src1 + 4);
        *(u16x8*)(&As_[off0]) = cvt8v(a0, a1);
        *(u16x8*)(&As_[off1]) = cvt8v(b0, b1);
    }
    __syncthreads();

    int cur = 0;
    for (int ks = 0; ks < 16; ks++) {
        const bool more = (ks < 15);
        f32x4v n00, n01, n10, n11;
        if (more) {   // issue next chunk's loads (overlap with compute)
            const float* s0 = src0 + (ks + 1) * 64;
            const float* s1 = src1 + (ks + 1) * 64;
            n00 = *(const f32x4v*)s0;
            n01 = *(const f32x4v*)(s0 + 4);
            n10 = *(const f32x4v*)s1;
            n11 = *(const f32x4v*)(s1 + 4);
        }
        // compute step ks from buf^cur
        const unsigned short* Ac = As_ + cur * 8192;
#pragma unroll
        for (int kk = 0; kk < 2; kk++) {
            bf16x8 a[2];
#pragma unroll
            for (int st = 0; st < 2; st++) {
                int arow = (mp * 2 + st) * 16 + l16;
                a[st] = load8_bf(&Ac[arow * 64 + (((kk * 4 + quad) ^ (arow & 7)) * 8)]);
            }
#pragma unroll
            for (int i = 0; i < 6; i++) {
                bf16x8 b = load8_bf(wb + (size_t)(i * 32 + ks * 2 + kk) * 512 + loff);
                acc[0][i] = __builtin_amdgcn_mfma_f32_16x16x32_bf16(a[0], b, acc[0][i], 0, 0, 0);
                acc[1][i] = __builtin_amdgcn_mfma_f32_16x16x32_bf16(a[1], b, acc[1][i], 0, 0, 0);
            }
        }
        if (more) {
            const int nxt = cur ^ 1;
            *(u16x8*)(&As_[nxt * 8192 + off0]) = cvt8v(n00, n01);
            *(u16x8*)(&As_[nxt * 8192 + off1]) = cvt8v(n10, n11);
            __syncthreads();
            cur = nxt;
        }
    }

    // ---- epilogue: per-wave chunk assembly in private LDS slice ----
    __syncthreads();                     // all staging reads done; reuse As_
    unsigned short* E = &As_[wave * 3072];   // 6 chunks x 512 u16
#pragma unroll
    for (int i = 0; i < 6; i++) {
        int nt = nh * 6 + i;
#pragma unroll
        for (int st = 0; st < 2; st++) {
#pragma unroll
            for (int r = 0; r < 4; r++) {
                unsigned short bv = f2bf(acc[st][i][r]);
                int ch, off;
                if (nt < 4) {            // Q (nh=0): chunks st*3 + part
                    ch  = st * 3 + (nt >> 1);
                    off = (quad * 4 + r) * 32 + ((nt & 1) * 2 + (l16 >> 3)) * 8 + (l16 & 7);
                } else if (nt < 8) {     // K
                    int nk = nt - 4;
                    ch  = (nh == 0) ? (st * 3 + 2) : st;   // part0 w/ Q-wave, part1 w/ V-wave
                    off = (quad * 4 + r) * 32 + ((nk & 1) * 2 + (l16 >> 3)) * 8 + (l16 & 7);
                } else {                 // V (nh=1): chunks 2+ht, spans both strips
                    int w32 = st * 16 + quad * 4 + r;
                    ch  = 2 + (nt - 8);
                    off = l16 * 32 + (w32 >> 3) * 8 + (w32 & 7);
                }
                E[ch * 512 + off] = bv;
            }
        }
    }
    __syncthreads();                     // order wave's ds_writes before reads

    // copy out: 6 chunks x (64 lanes x 16B = 1KB contiguous)
#pragma unroll
    for (int c = 0; c < 6; c++) {
        unsigned short* dst;
        if (nh == 0) {
            int st = (c < 3) ? 0 : 1;
            int j  = c - st * 3;
            int t16 = t16_0 + mp * 2 + st;
            if (j < 2) dst = Qf + ((size_t)(bb * 128 + t16) * 2 + j) * 512;
            else       dst = Kf + ((size_t)(bb * 128 + t16) * 2 + 0) * 512;
        } else {
            if (c < 2) {
                int t16 = t16_0 + mp * 2 + c;
                dst = Kf + ((size_t)(bb * 128 + t16) * 2 + 1) * 512;
            } else {
                int s32 = s32_0 + mp;
                dst = Vf + ((size_t)(bb * 64 + s32) * 4 + (c - 2)) * 512;
            }
        }
        *(u16x8*)(dst + lane * 8) = *(const u16x8*)(&E[c * 512 + lane * 8]);
    }
}

// ---------------------------------------------------------------------------
// Kernel 2: flash attention (R8 version: 32 q-rows/block, 4-way KV split,
// XCD batch-affinity, fragment-major loads) — unchanged, no nt hints.
// ---------------------------------------------------------------------------
#define PROW 33   // u32 per P^T row
#define OMS2 66   // u16 per O-merge row

__global__ __launch_bounds__(256) void attn(
        const unsigned short* __restrict__ Qf,
        const unsigned short* __restrict__ Kf,
        const unsigned short* __restrict__ Vf,
        float* __restrict__ out) {
    __shared__ unsigned int ps_[4 * 32 * PROW];     // 16.9 KB
    __shared__ unsigned short Om_[4 * 32 * OMS2];   // 16.9 KB
    __shared__ float mred_[4][32];
    __shared__ float lred_[4][32];

    const int tid  = threadIdx.x;
    const int wave = tid >> 6;            // KV-split index 0..3
    const int lane = tid & 63;
    const int l16  = lane & 15;
    const int quad = lane >> 4;
    const int b    = blockIdx.x & 7;      // XCD-affinity: batch = XCD
    const int qt32 = blockIdx.x >> 3;     // 0..63
    const int q0   = qt32 * 32;
    const int tdiag = qt32 >> 1;          // diagonal 64-key tile index

    const int loff = l16 * 32 + quad * 8;

    // Q as B-operand, two q-groups
    bf16x8 qf[2][2];
#pragma unroll
    for (int qg = 0; qg < 2; qg++) {
        const unsigned short* Qfb = Qf + (size_t)((b * 128 + qt32 * 2 + qg) * 2) * 512;
        qf[qg][0] = load8_bf(Qfb + loff);
        qf[qg][1] = load8_bf(Qfb + 512 + loff);
    }

    f32x4 o[8];   // [qg*4 + ht]
#pragma unroll
    for (int i = 0; i < 8; i++) o[i] = (f32x4){0.f, 0.f, 0.f, 0.f};
    float m_run[2] = {-1e30f, -1e30f}, l_run[2] = {0.f, 0.f};

    const float scale = 0.125f;  // 1/sqrt(H)
    const unsigned short* Kfb = Kf + (size_t)b * 128 * 1024;
    const unsigned short* Vfb = Vf + (size_t)b * 64 * 2048;
    unsigned int* Pw = &ps_[wave * 32 * PROW];

    for (int t = wave; t <= tdiag; t += 4) {
        // V^T A-frags: contiguous 1KB loads, issued EARLY (softmax-independent)
        bf16x8 vf[8];
#pragma unroll
        for (int ks = 0; ks < 2; ks++)
#pragma unroll
            for (int ht = 0; ht < 4; ht++)
                vf[ht * 2 + ks] = load8_bf(
                    Vfb + ((size_t)(t * 2 + ks) * 4 + ht) * 512 + loff);

        // S^T = K * Q^T for both q-groups (K frags shared)
        f32x4 s[2][4];
#pragma unroll
        for (int nt = 0; nt < 4; nt++) {
            const unsigned short* kp = Kfb + (size_t)(t * 4 + nt) * 1024;
            bf16x8 kf0 = load8_bf(kp + loff);
            bf16x8 kf1 = load8_bf(kp + 512 + loff);
#pragma unroll
            for (int qg = 0; qg < 2; qg++) {
                f32x4 z = (f32x4){0.f, 0.f, 0.f, 0.f};
                z = __builtin_amdgcn_mfma_f32_16x16x32_bf16(kf0, qf[qg][0], z, 0, 0, 0);
                z = __builtin_amdgcn_mfma_f32_16x16x32_bf16(kf1, qf[qg][1], z, 0, 0, 0);
                s[qg][nt] = z;   // S^T[s = t*64+nt*16+quad*4+r][q = q0+qg*16+l16]
            }
        }

#pragma unroll
        for (int qg = 0; qg < 2; qg++)
#pragma unroll
            for (int nt = 0; nt < 4; nt++)
#pragma unroll
                for (int r = 0; r < 4; r++) s[qg][nt][r] *= scale;

        if (t == tdiag) {   // causal: mask s > q
#pragma unroll
            for (int qg = 0; qg < 2; qg++) {
                int q = q0 + qg * 16 + l16;
#pragma unroll
                for (int nt = 0; nt < 4; nt++)
#pragma unroll
                    for (int r = 0; r < 4; r++) {
                        int key = t * 64 + nt * 16 + quad * 4 + r;
                        if (key > q) s[qg][nt][r] = -1e30f;
                    }
            }
        }

        // per-lane softmax per q-group: in-lane tree + 2 cross-quad shuffles
#pragma unroll
        for (int qg = 0; qg < 2; qg++) {
            float m0 = fmaxf(fmaxf(s[qg][0][0], s[qg][0][1]), fmaxf(s[qg][0][2], s[qg][0][3]));
            float m1 = fmaxf(fmaxf(s[qg][1][0], s[qg][1][1]), fmaxf(s[qg][1][2], s[qg][1][3]));
            float m2 = fmaxf(fmaxf(s[qg][2][0], s[qg][2][1]), fmaxf(s[qg][2][2], s[qg][2][3]));
            float m3 = fmaxf(fmaxf(s[qg][3][0], s[qg][3][1]), fmaxf(s[qg][3][2], s[qg][3][3]));
            float mx = fmaxf(fmaxf(m0, m1), fmaxf(m2, m3));
            mx = fmaxf(mx, __shfl_xor(mx, 16));
            mx = fmaxf(mx, __shfl_xor(mx, 32));
            const float m_new = fmaxf(m_run[qg], mx);
            const float alpha = __expf(m_run[qg] - m_new);
            m_run[qg] = m_new;

            float rs = 0.f;
#pragma unroll
            for (int nt = 0; nt < 4; nt++) {
#pragma unroll
                for (int i = 0; i < 2; i++) {
                    float p0 = __expf(s[qg][nt][2 * i]     - m_new);
                    float p1 = __expf(s[qg][nt][2 * i + 1] - m_new);
                    rs += p0 + p1;
                    Pw[(qg * 16 + l16) * PROW + nt * 8 + quad * 2 + i] = pack2(p0, p1);
                }
            }
            rs += __shfl_xor(rs, 16);
            rs += __shfl_xor(rs, 32);
            l_run[qg] = l_run[qg] * alpha + rs;

#pragma unroll
            for (int ht = 0; ht < 4; ht++)
#pragma unroll
                for (int r = 0; r < 4; r++) o[qg * 4 + ht][r] *= alpha;
        }

        // O^T += V^T * P^T (V frags shared across q-groups)
#pragma unroll
        for (int ks = 0; ks < 2; ks++) {
#pragma unroll
            for (int qg = 0; qg < 2; qg++) {
                bf16x8 pB = __builtin_bit_cast(bf16x8,
                    *(const u16x8*)(&Pw[(qg * 16 + l16) * PROW + ks * 16 + quad * 4]));
#pragma unroll
                for (int ht = 0; ht < 4; ht++)
                    o[qg * 4 + ht] = __builtin_amdgcn_mfma_f32_16x16x32_bf16(
                        vf[ht * 2 + ks], pB, o[qg * 4 + ht], 0, 0, 0);
            }
        }
    }

    // ---- 4-way LSE merge (O partials bf16) ----
#pragma unroll
    for (int qg = 0; qg < 2; qg++) {
#pragma unroll
        for (int ht = 0; ht < 4; ht++)
#pragma unroll
            for (int r = 0; r < 4; r++)
                Om_[(wave * 32 + qg * 16 + l16) * OMS2 + ht * 16 + quad * 4 + r] =
                    f2bf(o[qg * 4 + ht][r]);
        if (quad == 0) {
            mred_[wave][qg * 16 + l16] = m_run[qg];
            lred_[wave][qg * 16 + l16] = l_run[qg];
        }
    }
    __syncthreads();

    // finalize: thread -> (q, h); coalesced out write
    const int hcol = tid & 63;
    const int qr0  = tid >> 6;   // 0..3
#pragma unroll
    for (int qq = 0; qq < 8; qq++) {
        const int q = qr0 + qq * 4;
        float M = -1e30f;
#pragma unroll
        for (int w = 0; w < 4; w++) M = fmaxf(M, mred_[w][q]);
        float lt = 0.f, ov = 0.f;
#pragma unroll
        for (int w = 0; w < 4; w++) {
            float e = __expf(mred_[w][q] - M);
            lt += e * lred_[w][q];
            ov += e * bf2f(Om_[(w * 32 + q) * OMS2 + hcol]);
        }
        out[((size_t)b * T_ + q0 + q) * H_ + hcol] = ov / lt;
    }
}

// ---------------------------------------------------------------------------
extern "C" void kernel_launch(void* const* d_in, const int* in_sizes, int n_in,
                              void* d_out, int out_size, void* d_ws, size_t ws_size,
                              hipStream_t stream) {
    const float* x  = (const float*)d_in[0];
    const float* Wq = (const float*)d_in[1];
    const float* Wk = (const float*)d_in[2];
    const float* Wv = (const float*)d_in[3];
    float* out = (float*)d_out;

    unsigned short* Qf  = (unsigned short*)d_ws;
    unsigned short* Kf  = Qf + (size_t)B_ * T_ * H_;
    unsigned short* Vf  = Kf + (size_t)B_ * T_ * H_;
    unsigned short* Wtf = Vf + (size_t)B_ * T_ * H_;

    cast_weights<<<(192 * C_) / 256, 256, 0, stream>>>(Wq, Wk, Wv, Wtf);
    qkv_proj<<<B_ * T_ / 128, 512, 0, stream>>>(x, Wtf, Qf, Kf, Vf);
    attn<<<B_ * (T_ / 32), 256, 0, stream>>>(Qf, Kf, Vf, out);
}

// Round 12
// 141.436 us; speedup vs baseline: 1.1861x; 1.1861x over previous
//
#include <hip/hip_runtime.h>

// Problem constants (reference: B=8, T=2048, C=1024, H=64)
#define B_ 8
#define T_ 2048
#define C_ 1024
#define H_ 64

typedef __bf16 bf16x8 __attribute__((ext_vector_type(8)));
typedef float  f32x4  __attribute__((ext_vector_type(4)));
typedef unsigned short u16x8 __attribute__((ext_vector_type(8)));

// round-half-up f32 -> bf16 bits
__device__ __forceinline__ unsigned short f2bf(float f) {
    unsigned u = __builtin_bit_cast(unsigned, f);
    u += 0x8000u;
    return (unsigned short)(u >> 16);
}

__device__ __forceinline__ float bf2f(unsigned short v) {
    unsigned u = ((unsigned)v) << 16;
    return __builtin_bit_cast(float, u);
}

__device__ __forceinline__ unsigned pack2(float lo, float hi) {
    unsigned a = __builtin_bit_cast(unsigned, lo) + 0x8000u;
    unsigned b = __builtin_bit_cast(unsigned, hi) + 0x8000u;
    return (a >> 16) | (b & 0xffff0000u);
}

union U8 { unsigned u32[4]; u16x8 v; };

__device__ __forceinline__ u16x8 cvt8(float4 f0, float4 f1) {
    U8 r;
    r.u32[0] = pack2(f0.x, f0.y);
    r.u32[1] = pack2(f0.z, f0.w);
    r.u32[2] = pack2(f1.x, f1.y);
    r.u32[3] = pack2(f1.z, f1.w);
    return r.v;
}

__device__ __forceinline__ bf16x8 load8_bf(const unsigned short* p) {
    return __builtin_bit_cast(bf16x8, *(const u16x8*)p);
}

// Fragment-major layouts for attention (contiguous 1KB-per-wave loads):
//   Qf/Kf[b][t16][part][l16*32 + quad*8 + j]   (t16 = seq/16, part = h/32)
//   Vf[b][s32][ht][l16*32 + quad*8 + j]        (s32 = seq/32, ht = h/16)

// ---------------------------------------------------------------------------
// Kernel 0: pack Wq,Wk,Wv (fp32 [C][H]) into ROW-major transposed bf16
// Wt[192][1024] (what qkv's LDS staging wants; coalesced writes over c).
// ---------------------------------------------------------------------------
__global__ void cast_weights(const float* __restrict__ Wq,
                             const float* __restrict__ Wk,
                             const float* __restrict__ Wv,
                             unsigned short* __restrict__ Wt) {
    int idx = blockIdx.x * blockDim.x + threadIdx.x;
    int w   = idx >> 16;            // / (C*H) = 65536
    int rem = idx & 0xffff;
    int c   = rem & (C_ - 1);       // fastest -> coalesced Wt writes
    int h   = rem >> 10;
    const float* W = (w == 0) ? Wq : (w == 1) ? Wk : Wv;
    Wt[(size_t)(w * H_ + h) * C_ + c] = f2bf(W[(size_t)c * H_ + h]);
}

// ---------------------------------------------------------------------------
// Kernel 1: fused QKV projection, v11 = v6 structure (best measured TLP:
// 1024 blocks x 256 thr = 16 waves/CU) + v8-style coalesced epilogue.
// Block = 32 rows x 96 cols (nh = n-half); 4 waves (ms = row strip 0..1,
// nsub = 3-n-tile group 0..1).  Double-buffered LDS staging of A (x->bf16)
// and B (Wt), XOR-swizzled; 16 k-steps of BK=64, 6 MFMA/wave/step.
// Epilogue: accs -> 6 fragment-major 1KB chunks assembled in LDS (reuses
// staging buffer), one barrier, then 384 contiguous 16B granule stores.
// ---------------------------------------------------------------------------
#define ABUF 2048   // 32x64 bf16
#define BBUF 6144   // 96x64 bf16

__global__ __launch_bounds__(256) void qkv_proj(
        const float* __restrict__ x,
        const unsigned short* __restrict__ Wt,
        unsigned short* __restrict__ Qf,
        unsigned short* __restrict__ Kf,
        unsigned short* __restrict__ Vf) {
    __shared__ __attribute__((aligned(16))) unsigned short As_[2 * ABUF];  //  8 KB
    __shared__ __attribute__((aligned(16))) unsigned short Bs_[2 * BBUF];  // 24 KB

    const int tid  = threadIdx.x;
    const int wave = tid >> 6;
    const int lane = tid & 63;
    const int l16  = lane & 15;
    const int quad = lane >> 4;
    const int ms   = wave >> 1;          // row strip 0..1
    const int nsub = wave & 1;           // n-sub: 3 n-tiles each
    const int mb   = blockIdx.x >> 1;
    const int nh   = blockIdx.x & 1;     // n-half of 192 cols
    const size_t r0 = (size_t)mb * 32;
    const int bb    = (int)(r0 >> 11);
    const int tloc0 = (int)(r0 & (T_ - 1));
    const int t16_0 = tloc0 >> 4;
    const int s32_0 = tloc0 >> 5;

    // staging roles
    const int srow = tid >> 3, sg = tid & 7;
    const float* sa_src = x + (r0 + srow) * C_ + sg * 8;
    const unsigned short* wb = Wt + (size_t)(nh * 96) * C_;
    const int a_off = srow * 64 + ((sg ^ (srow & 7)) * 8);  // XOR-swizzled; B: +p*2048

    f32x4 acc[3];
#pragma unroll
    for (int i = 0; i < 3; i++) acc[i] = (f32x4){0.f, 0.f, 0.f, 0.f};

    const int sw = l16 & 7;

    // prologue: stage k-step 0 into buf 0
    {
        float4 f0 = *(const float4*)(sa_src);
        float4 f1 = *(const float4*)(sa_src + 4);
        *(u16x8*)(&As_[a_off]) = cvt8(f0, f1);
#pragma unroll
        for (int p = 0; p < 3; p++) {
            u16x8 v = *(const u16x8*)(wb + (size_t)(p * 32 + srow) * C_ + sg * 8);
            *(u16x8*)(&Bs_[p * 2048 + a_off]) = v;
        }
    }
    __syncthreads();

    int cur = 0;
    for (int ks = 0; ks < 16; ks++) {
        const int k1 = (ks + 1) * 64;
        const bool more = (k1 < C_);
        float4 na0, na1;
        u16x8 nb0, nb1, nb2;
        if (more) {   // issue next tile's loads (overlap with compute)
            na0 = *(const float4*)(sa_src + k1);
            na1 = *(const float4*)(sa_src + k1 + 4);
            nb0 = *(const u16x8*)(wb + (size_t)(0 * 32 + srow) * C_ + k1 + sg * 8);
            nb1 = *(const u16x8*)(wb + (size_t)(1 * 32 + srow) * C_ + k1 + sg * 8);
            nb2 = *(const u16x8*)(wb + (size_t)(2 * 32 + srow) * C_ + k1 + sg * 8);
        }
        // compute tile ks from buf^cur
        const unsigned short* Ac = As_ + cur * ABUF;
        const unsigned short* Bc = Bs_ + cur * BBUF;
        const int arow = ms * 16 + l16;
        bf16x8 a0 = load8_bf(&Ac[arow * 64 + ((quad ^ sw) * 8)]);
        bf16x8 a1 = load8_bf(&Ac[arow * 64 + (((quad + 4) ^ sw) * 8)]);
#pragma unroll
        for (int i = 0; i < 3; i++) {
            int brow = (nsub * 3 + i) * 16 + l16;
            bf16x8 b0 = load8_bf(&Bc[brow * 64 + ((quad ^ sw) * 8)]);
            bf16x8 b1 = load8_bf(&Bc[brow * 64 + (((quad + 4) ^ sw) * 8)]);
            acc[i] = __builtin_amdgcn_mfma_f32_16x16x32_bf16(a0, b0, acc[i], 0, 0, 0);
            acc[i] = __builtin_amdgcn_mfma_f32_16x16x32_bf16(a1, b1, acc[i], 0, 0, 0);
        }
        if (more) {
            const int nxt = cur ^ 1;
            *(u16x8*)(&As_[nxt * ABUF + a_off]) = cvt8(na0, na1);
            *(u16x8*)(&Bs_[nxt * BBUF + 0 * 2048 + a_off]) = nb0;
            *(u16x8*)(&Bs_[nxt * BBUF + 1 * 2048 + a_off]) = nb1;
            *(u16x8*)(&Bs_[nxt * BBUF + 2 * 2048 + a_off]) = nb2;
            __syncthreads();
            cur = nxt;
        }
    }

    // ---- epilogue: assemble 6 fragment-major 1KB chunks in LDS ----
    // chunk table nh=0: 0..3 = Q(st=ch>>1, part=ch&1), 4..5 = K(st=ch-4, p0)
    //             nh=1: 0..1 = K(st=ch, p1), 2..5 = V(ht=ch-2)
    __syncthreads();                     // last tile's ds_reads done; reuse As_
    unsigned short* E = As_;             // 6 chunks x 512 u16 = 6 KB (fits 8 KB)
#pragma unroll
    for (int i = 0; i < 3; i++) {
        int nt = nh * 6 + nsub * 3 + i;  // global n-tile 0..11
#pragma unroll
        for (int r = 0; r < 4; r++) {
            unsigned short bv = f2bf(acc[i][r]);
            int ch, off;
            if (nt < 4) {                // Q (nh=0)
                ch  = ms * 2 + (nt >> 1);
                off = (quad * 4 + r) * 32 + ((nt & 1) * 2 + (l16 >> 3)) * 8 + (l16 & 7);
            } else if (nt < 8) {         // K
                int nk = nt - 4;
                ch  = (nh == 0) ? (4 + ms) : ms;
                off = (quad * 4 + r) * 32 + ((nk & 1) * 2 + (l16 >> 3)) * 8 + (l16 & 7);
            } else {                     // V (nh=1)
                int w32 = ms * 16 + quad * 4 + r;
                ch  = 2 + (nt - 8);
                off = l16 * 32 + (w32 >> 3) * 8 + (w32 & 7);
            }
            E[ch * 512 + off] = bv;
        }
    }
    __syncthreads();

    // copy out: 6 chunks x 64 granules of 16B (384 granules, 256 threads)
#pragma unroll
    for (int it = 0; it < 2; it++) {
        int gi = it * 256 + tid;
        if (gi < 384) {
            int ch = gi >> 6;
            int g  = gi & 63;
            unsigned short* dst;
            if (nh == 0) {
                if (ch < 4) dst = Qf + ((size_t)(bb * 128 + t16_0 + (ch >> 1)) * 2 + (ch & 1)) * 512;
                else        dst = Kf + ((size_t)(bb * 128 + t16_0 + (ch - 4)) * 2 + 0) * 512;
            } else {
                if (ch < 2) dst = Kf + ((size_t)(bb * 128 + t16_0 + ch) * 2 + 1) * 512;
                else        dst = Vf + ((size_t)(bb * 64 + s32_0) * 4 + (ch - 2)) * 512;
            }
            *(u16x8*)(dst + g * 8) = *(const u16x8*)(&E[ch * 512 + g * 8]);
        }
    }
}

// ---------------------------------------------------------------------------
// Kernel 2: flash attention (R8 best: 32 q-rows/block, 4-way KV split,
// XCD batch-affinity, fragment-major contiguous loads) — unchanged.
// ---------------------------------------------------------------------------
#define PROW 33   // u32 per P^T row
#define OMS2 66   // u16 per O-merge row

__global__ __launch_bounds__(256) void attn(
        const unsigned short* __restrict__ Qf,
        const unsigned short* __restrict__ Kf,
        const unsigned short* __restrict__ Vf,
        float* __restrict__ out) {
    __shared__ unsigned int ps_[4 * 32 * PROW];     // 16.9 KB
    __shared__ unsigned short Om_[4 * 32 * OMS2];   // 16.9 KB
    __shared__ float mred_[4][32];
    __shared__ float lred_[4][32];

    const int tid  = threadIdx.x;
    const int wave = tid >> 6;            // KV-split index 0..3
    const int lane = tid & 63;
    const int l16  = lane & 15;
    const int quad = lane >> 4;
    const int b    = blockIdx.x & 7;      // XCD-affinity: batch = XCD
    const int qt32 = blockIdx.x >> 3;     // 0..63
    const int q0   = qt32 * 32;
    const int tdiag = qt32 >> 1;          // diagonal 64-key tile index

    const int loff = l16 * 32 + quad * 8;

    // Q as B-operand, two q-groups
    bf16x8 qf[2][2];
#pragma unroll
    for (int qg = 0; qg < 2; qg++) {
        const unsigned short* Qfb = Qf + (size_t)((b * 128 + qt32 * 2 + qg) * 2) * 512;
        qf[qg][0] = load8_bf(Qfb + loff);
        qf[qg][1] = load8_bf(Qfb + 512 + loff);
    }

    f32x4 o[8];   // [qg*4 + ht]
#pragma unroll
    for (int i = 0; i < 8; i++) o[i] = (f32x4){0.f, 0.f, 0.f, 0.f};
    float m_run[2] = {-1e30f, -1e30f}, l_run[2] = {0.f, 0.f};

    const float scale = 0.125f;  // 1/sqrt(H)
    const unsigned short* Kfb = Kf + (size_t)b * 128 * 1024;
    const unsigned short* Vfb = Vf + (size_t)b * 64 * 2048;
    unsigned int* Pw = &ps_[wave * 32 * PROW];

    for (int t = wave; t <= tdiag; t += 4) {
        // V^T A-frags: contiguous 1KB loads, issued EARLY (softmax-independent)
        bf16x8 vf[8];
#pragma unroll
        for (int ks = 0; ks < 2; ks++)
#pragma unroll
            for (int ht = 0; ht < 4; ht++)
                vf[ht * 2 + ks] = load8_bf(
                    Vfb + ((size_t)(t * 2 + ks) * 4 + ht) * 512 + loff);

        // S^T = K * Q^T for both q-groups (K frags shared)
        f32x4 s[2][4];
#pragma unroll
        for (int nt = 0; nt < 4; nt++) {
            const unsigned short* kp = Kfb + (size_t)(t * 4 + nt) * 1024;
            bf16x8 kf0 = load8_bf(kp + loff);
            bf16x8 kf1 = load8_bf(kp + 512 + loff);
#pragma unroll
            for (int qg = 0; qg < 2; qg++) {
                f32x4 z = (f32x4){0.f, 0.f, 0.f, 0.f};
                z = __builtin_amdgcn_mfma_f32_16x16x32_bf16(kf0, qf[qg][0], z, 0, 0, 0);
                z = __builtin_amdgcn_mfma_f32_16x16x32_bf16(kf1, qf[qg][1], z, 0, 0, 0);
                s[qg][nt] = z;   // S^T[s = t*64+nt*16+quad*4+r][q = q0+qg*16+l16]
            }
        }

#pragma unroll
        for (int qg = 0; qg < 2; qg++)
#pragma unroll
            for (int nt = 0; nt < 4; nt++)
#pragma unroll
                for (int r = 0; r < 4; r++) s[qg][nt][r] *= scale;

        if (t == tdiag) {   // causal: mask s > q
#pragma unroll
            for (int qg = 0; qg < 2; qg++) {
                int q = q0 + qg * 16 + l16;
#pragma unroll
                for (int nt = 0; nt < 4; nt++)
#pragma unroll
                    for (int r = 0; r < 4; r++) {
                        int key = t * 64 + nt * 16 + quad * 4 + r;
                        if (key > q) s[qg][nt][r] = -1e30f;
                    }
            }
        }

        // per-lane softmax per q-group: in-lane tree + 2 cross-quad shuffles
#pragma unroll
        for (int qg = 0; qg < 2; qg++) {
            float m0 = fmaxf(fmaxf(s[qg][0][0], s[qg][0][1]), fmaxf(s[qg][0][2], s[qg][0][3]));
            float m1 = fmaxf(fmaxf(s[qg][1][0], s[qg][1][1]), fmaxf(s[qg][1][2], s[qg][1][3]));
            float m2 = fmaxf(fmaxf(s[qg][2][0], s[qg][2][1]), fmaxf(s[qg][2][2], s[qg][2][3]));
            float m3 = fmaxf(fmaxf(s[qg][3][0], s[qg][3][1]), fmaxf(s[qg][3][2], s[qg][3][3]));
            float mx = fmaxf(fmaxf(m0, m1), fmaxf(m2, m3));
            mx = fmaxf(mx, __shfl_xor(mx, 16));
            mx = fmaxf(mx, __shfl_xor(mx, 32));
            const float m_new = fmaxf(m_run[qg], mx);
            const float alpha = __expf(m_run[qg] - m_new);
            m_run[qg] = m_new;

            float rs = 0.f;
#pragma unroll
            for (int nt = 0; nt < 4; nt++) {
#pragma unroll
                for (int i = 0; i < 2; i++) {
                    float p0 = __expf(s[qg][nt][2 * i]     - m_new);
                    float p1 = __expf(s[qg][nt][2 * i + 1] - m_new);
                    rs += p0 + p1;
                    Pw[(qg * 16 + l16) * PROW + nt * 8 + quad * 2 + i] = pack2(p0, p1);
                }
            }
            rs += __shfl_xor(rs, 16);
            rs += __shfl_xor(rs, 32);
            l_run[qg] = l_run[qg] * alpha + rs;

#pragma unroll
            for (int ht = 0; ht < 4; ht++)
#pragma unroll
                for (int r = 0; r < 4; r++) o[qg * 4 + ht][r] *= alpha;
        }

        // O^T += V^T * P^T (V frags shared across q-groups)
#pragma unroll
        for (int ks = 0; ks < 2; ks++) {
#pragma unroll
            for (int qg = 0; qg < 2; qg++) {
                bf16x8 pB = __builtin_bit_cast(bf16x8,
                    *(const u16x8*)(&Pw[(qg * 16 + l16) * PROW + ks * 16 + quad * 4]));
#pragma unroll
                for (int ht = 0; ht < 4; ht++)
                    o[qg * 4 + ht] = __builtin_amdgcn_mfma_f32_16x16x32_bf16(
                        vf[ht * 2 + ks], pB, o[qg * 4 + ht], 0, 0, 0);
            }
        }
    }

    // ---- 4-way LSE merge (O partials bf16) ----
#pragma unroll
    for (int qg = 0; qg < 2; qg++) {
#pragma unroll
        for (int ht = 0; ht < 4; ht++)
#pragma unroll
            for (int r = 0; r < 4; r++)
                Om_[(wave * 32 + qg * 16 + l16) * OMS2 + ht * 16 + quad * 4 + r] =
                    f2bf(o[qg * 4 + ht][r]);
        if (quad == 0) {
            mred_[wave][qg * 16 + l16] = m_run[qg];
            lred_[wave][qg * 16 + l16] = l_run[qg];
        }
    }
    __syncthreads();

    // finalize: thread -> (q, h); coalesced out write
    const int hcol = tid & 63;
    const int qr0  = tid >> 6;   // 0..3
#pragma unroll
    for (int qq = 0; qq < 8; qq++) {
        const int q = qr0 + qq * 4;
        float M = -1e30f;
#pragma unroll
        for (int w = 0; w < 4; w++) M = fmaxf(M, mred_[w][q]);
        float lt = 0.f, ov = 0.f;
#pragma unroll
        for (int w = 0; w < 4; w++) {
            float e = __expf(mred_[w][q] - M);
            lt += e * lred_[w][q];
            ov += e * bf2f(Om_[(w * 32 + q) * OMS2 + hcol]);
        }
        out[((size_t)b * T_ + q0 + q) * H_ + hcol] = ov / lt;
    }
}

// ---------------------------------------------------------------------------
extern "C" void kernel_launch(void* const* d_in, const int* in_sizes, int n_in,
                              void* d_out, int out_size, void* d_ws, size_t ws_size,
                              hipStream_t stream) {
    const float* x  = (const float*)d_in[0];
    const float* Wq = (const float*)d_in[1];
    const float* Wk = (const float*)d_in[2];
    const float* Wv = (const float*)d_in[3];
    float* out = (float*)d_out;

    unsigned short* Qf = (unsigned short*)d_ws;
    unsigned short* Kf = Qf + (size_t)B_ * T_ * H_;
    unsigned short* Vf = Kf + (size_t)B_ * T_ * H_;
    unsigned short* Wt = Vf + (size_t)B_ * T_ * H_;

    cast_weights<<<(3 * C_ * H_) / 256, 256, 0, stream>>>(Wq, Wk, Wv, Wt);
    qkv_proj<<<(B_ * T_ / 32) * 2, 256, 0, stream>>>(x, Wt, Qf, Kf, Vf);
    attn<<<B_ * (T_ / 32), 256, 0, stream>>>(Qf, Kf, Vf, out);
}